// Round 12
// baseline (230.868 us; speedup 1.0000x reference)
//
#include <hip/hip_runtime.h>
#include <math.h>

typedef unsigned short u16;
typedef unsigned int u32;
typedef _Float16 f16;
typedef f16 f16x8 __attribute__((ext_vector_type(8)));
typedef __fp16 hp16x2 __attribute__((ext_vector_type(2)));
typedef float f32x4 __attribute__((ext_vector_type(4)));
typedef float f32x16 __attribute__((ext_vector_type(16)));

#define SEQ   2048
#define NH    16
#define HD    64
#define EMB   1024
#define NQKV  3072
#define BATCH 2
#define QSCALE 0.18033688f  // 0.125 * log2(e)

__device__ __forceinline__ u16 f2h(float f) {
  union { f16 h; u16 u; } w; w.h = (f16)f; return w.u;
}
__device__ __forceinline__ u32 pk2(float a, float b) {
  union { hp16x2 h; u32 u; } w; w.h = __builtin_amdgcn_cvt_pkrtz(a, b); return w.u;
}

// global -> LDS direct copy, 16 B per lane; dst = wave-uniform base + lane*16
__device__ __forceinline__ void gload16(const void* g, void* l) {
  __builtin_amdgcn_global_load_lds(
      (const __attribute__((address_space(1))) unsigned int*)g,
      (__attribute__((address_space(3))) unsigned int*)l, 16, 0, 0);
}

// ---------------------------------------------------------------------------
// Pre-pass: X fp32 -> f16 (flat copy)
// ---------------------------------------------------------------------------
__global__ __launch_bounds__(256) void cvt_x(const float* __restrict__ X,
                                             u16* __restrict__ Xh) {
  const size_t i = ((size_t)blockIdx.x * 256 + threadIdx.x) * 8;
  float4 a = *reinterpret_cast<const float4*>(&X[i]);
  float4 b = *reinterpret_cast<const float4*>(&X[i + 4]);
  union { u32 u[4]; float4 f; } pk;
  pk.u[0] = pk2(a.x, a.y); pk.u[1] = pk2(a.z, a.w);
  pk.u[2] = pk2(b.x, b.y); pk.u[3] = pk2(b.z, b.w);
  *reinterpret_cast<float4*>(&Xh[i]) = pk.f;
}

// ---------------------------------------------------------------------------
// Pre-pass: W[K][N] fp32 -> Wt[N][K] f16 (transpose + convert), 64x64 tiles
// ---------------------------------------------------------------------------
__global__ __launch_bounds__(256) void cvt_wt(const float* __restrict__ W,
                                              u16* __restrict__ Wt,
                                              int K, int N) {
  __shared__ u16 T[64][68];
  const int n0 = blockIdx.x << 6, k0 = blockIdx.y << 6;
  const int t = threadIdx.x;
  const int rr = t >> 4, cc = (t & 15) << 2;
#pragma unroll
  for (int p = 0; p < 4; p++) {
    const int kr = p * 16 + rr;
    float4 v = *reinterpret_cast<const float4*>(&W[(size_t)(k0 + kr) * N + n0 + cc]);
    T[cc + 0][kr] = f2h(v.x); T[cc + 1][kr] = f2h(v.y);
    T[cc + 2][kr] = f2h(v.z); T[cc + 3][kr] = f2h(v.w);
  }
  __syncthreads();
#pragma unroll
  for (int p = 0; p < 4; p++) {
    const int nr = p * 16 + rr;
    union { u16 s[4]; unsigned long long d; } o;
    o.s[0] = T[nr][cc + 0]; o.s[1] = T[nr][cc + 1];
    o.s[2] = T[nr][cc + 2]; o.s[3] = T[nr][cc + 3];
    *reinterpret_cast<unsigned long long*>(&Wt[(size_t)(n0 + nr) * K + k0 + cc]) = o.d;
  }
}

// ---------------------------------------------------------------------------
// m97-style MFMA GEMM core (unchanged from R10)
// ---------------------------------------------------------------------------
__device__ __forceinline__ void gemm_core(const u16* __restrict__ Ag,
                                          const u16* __restrict__ Bg,
                                          int m0, int n0, int t,
                                          f32x4 acc[4][4]) {
  __shared__ __align__(16) u16 As[128 * 32];
  __shared__ __align__(16) u16 Bs[128 * 32];
  const int lane = t & 63, w = t >> 6;
  const int l15  = lane & 15, quad = lane >> 4;
  const int wm = w >> 1, wn = w & 1;
  const int srow  = lane >> 2;
  const int gslot = (lane & 3) ^ ((srow >> 1) & 3);
  const int xk    = (quad ^ ((l15 >> 1) & 3)) << 3;

  for (int k0 = 0; k0 < EMB; k0 += 32) {
    __syncthreads();
#pragma unroll
    for (int i = 0; i < 2; i++) {
      const int ca = w * 2 + i;
      const int arow = ca * 16 + srow;
      gload16(Ag + (size_t)(m0 + arow) * EMB + k0 + gslot * 8, &As[ca * 512]);
      gload16(Bg + (size_t)(n0 + arow) * EMB + k0 + gslot * 8, &Bs[ca * 512]);
    }
    __syncthreads();
    f16x8 af[4], bf[4];
#pragma unroll
    for (int s = 0; s < 4; s++)
      af[s] = *reinterpret_cast<const f16x8*>(&As[(wm * 64 + s * 16 + l15) * 32 + xk]);
#pragma unroll
    for (int s = 0; s < 4; s++)
      bf[s] = *reinterpret_cast<const f16x8*>(&Bs[(wn * 64 + s * 16 + l15) * 32 + xk]);
#pragma unroll
    for (int i = 0; i < 4; i++)
#pragma unroll
      for (int j = 0; j < 4; j++)
        acc[i][j] = __builtin_amdgcn_mfma_f32_16x16x32_f16(af[i], bf[j], acc[i][j], 0, 0, 0);
  }
}

// QKV: Xh @ Wt^T + bias -> q (scaled), k [B,H,N,D]; v TRANSPOSED [B,H,D,N]
__global__ __launch_bounds__(256) void k_qkv(const u16* __restrict__ Ag,
                                             const u16* __restrict__ Bg,
                                             const float* __restrict__ bias,
                                             u16* __restrict__ qo,
                                             u16* __restrict__ ko,
                                             u16* __restrict__ vo) {
  const int t = threadIdx.x;
  const int lane = t & 63, w = t >> 6;
  const int l15 = lane & 15, quad = lane >> 4;
  const int wm = w >> 1, wn = w & 1;
  const int m0 = blockIdx.y << 7, n0 = blockIdx.x << 7;
  f32x4 acc[4][4];
#pragma unroll
  for (int i = 0; i < 4; i++)
#pragma unroll
    for (int j = 0; j < 4; j++) acc[i][j] = (f32x4){0.f, 0.f, 0.f, 0.f};
  gemm_core(Ag, Bg, m0, n0, t, acc);
#pragma unroll
  for (int j = 0; j < 4; j++) {
    const int c = n0 + wn * 64 + j * 16 + l15;
    const int which = c >> 10, h = (c >> 6) & 15, d = c & 63;
    const float bv = bias[c];
    const float sc = (which == 0) ? QSCALE : 1.0f;
#pragma unroll
    for (int i = 0; i < 4; i++) {
#pragma unroll
      for (int r = 0; r < 4; r++) {
        const int m  = m0 + wm * 64 + i * 16 + quad * 4 + r;
        const int bb = m >> 11, n = m & (SEQ - 1);
        const u16 val = f2h((acc[i][j][r] + bv) * sc);
        if (which == 2)
          vo[(((size_t)bb * NH + h) * HD + d) * SEQ + n] = val;      // V^T
        else if (which == 1)
          ko[((((size_t)bb * NH + h) * SEQ) + n) * HD + d] = val;
        else
          qo[((((size_t)bb * NH + h) * SEQ) + n) * HD + d] = val;
      }
    }
  }
}

// Proj: ao[4096,1024] f16 @ Wpt^T + bias -> out fp32
__global__ __launch_bounds__(256) void k_proj(const u16* __restrict__ Ag,
                                              const u16* __restrict__ Bg,
                                              const float* __restrict__ bias,
                                              float* __restrict__ out) {
  const int t = threadIdx.x;
  const int lane = t & 63, w = t >> 6;
  const int l15 = lane & 15, quad = lane >> 4;
  const int wm = w >> 1, wn = w & 1;
  const int m0 = blockIdx.y << 7, n0 = blockIdx.x << 7;
  f32x4 acc[4][4];
#pragma unroll
  for (int i = 0; i < 4; i++)
#pragma unroll
    for (int j = 0; j < 4; j++) acc[i][j] = (f32x4){0.f, 0.f, 0.f, 0.f};
  gemm_core(Ag, Bg, m0, n0, t, acc);
#pragma unroll
  for (int j = 0; j < 4; j++) {
    const int c = n0 + wn * 64 + j * 16 + l15;
    const float bv = bias[c];
#pragma unroll
    for (int i = 0; i < 4; i++) {
#pragma unroll
      for (int r = 0; r < 4; r++) {
        const int m = m0 + wm * 64 + i * 16 + quad * 4 + r;
        out[(size_t)m * EMB + c] = acc[i][j][r] + bv;
      }
    }
  }
}

// ---------------------------------------------------------------------------
// MFMA flash attention, 32x32x16, S^T form, register-only P transform.
// Block = 64 q x (b,h), 2 waves (32 q each, full 64-kv tiles).
// C->A transform: per 16-kv window, 2 pre-selected shfl_xor(32) + cndmask.
// K/V^T double-buffered in LDS via global_load_lds; one barrier per tile.
// ---------------------------------------------------------------------------
__global__ __launch_bounds__(128) void k_attn(const u16* __restrict__ Qg,
                                              const u16* __restrict__ Kg,
                                              const u16* __restrict__ Vtg,
                                              u16* __restrict__ AO) {
  __shared__ __align__(16) u16 Ks[2][64 * 64];
  __shared__ __align__(16) u16 Vs[2][64 * 64];
  const int t    = threadIdx.x;          // 128 = 2 waves
  const int lane = t & 63, w = t >> 6;
  const int l31  = lane & 31, hi = lane >> 5;
  const int bh   = blockIdx.y;
  const int q0   = blockIdx.x << 6;
  const size_t base = (size_t)bh * SEQ * HD;

  // Q fragments (B-operand): qf[c] = Q[q0+32w+l31][c*16 + hi*8 + 0..7]
  f16x8 qf[4];
  {
    const u16* qp = Qg + base + (size_t)(q0 + 32 * w + l31) * HD + hi * 8;
#pragma unroll
    for (int c = 0; c < 4; c++) {
      union { float4 f; f16x8 v; } fu;
      fu.f = *reinterpret_cast<const float4*>(qp + c * 16);
      qf[c] = fu.v;
    }
  }

  f32x16 O0 = {}, O1 = {};
  float lsum = 0.f;
  const int fsw = (l31 >> 1) & 7;             // fragment-read swizzle
  const int srw = lane >> 3, ssl = lane & 7;  // staging row/slot

  auto stage = [&](int buf, int kt) {
#pragma unroll
    for (int i = 0; i < 4; i++) {
      const int ca  = w * 4 + i;              // 8-row chunk 0..7
      const int row = ca * 8 + srw;
      const int sg  = (ssl ^ ((row >> 1) & 7)) << 3;
      gload16(Kg  + base + (size_t)(kt + row) * HD + sg, &Ks[buf][ca * 512]);
      gload16(Vtg + base + (size_t)row * SEQ + kt + sg,  &Vs[buf][ca * 512]);
    }
  };

  stage(0, 0);
  int cur = 0;
  for (int kt = 0; kt < SEQ; kt += 64) {
    __syncthreads();                          // staging(cur) drained; prev compute done
    if (kt + 64 < SEQ) stage(cur ^ 1, kt + 64);
    const u16* Kb = Ks[cur];
    const u16* Vb = Vs[cur];

    f16x8 pA[4];                              // A-frags for the 4 kv windows
#pragma unroll
    for (int sk = 0; sk < 2; sk++) {
      f32x16 c = {};
#pragma unroll
      for (int cc = 0; cc < 4; cc++) {
        f16x8 kf = *reinterpret_cast<const f16x8*>(
            &Kb[(sk * 32 + l31) * 64 + (((cc * 2 + hi) ^ fsw) << 3)]);
        c = __builtin_amdgcn_mfma_f32_32x32x16_f16(kf, qf[cc], c, 0, 0, 0);
      }
      float p[16];
#pragma unroll
      for (int r = 0; r < 16; r++) {
        p[r] = exp2f(c[r]);
        lsum += p[r];
      }
      // per 16-kv window: pack pairs, exchange with lane^32, assemble A-frag
#pragma unroll
      for (int wd = 0; wd < 2; wd++) {        // window within subtile
        const float* pg = &p[wd * 8];
        const u32 A = pk2(pg[0], pg[1]);      // kv = 16wd + 4hi + {0,1}
        const u32 B = pk2(pg[2], pg[3]);      // kv = 16wd + 4hi + {2,3}
        const u32 C = pk2(pg[4], pg[5]);      // kv = 16wd + 8 + 4hi + {0,1}
        const u32 D = pk2(pg[6], pg[7]);      // kv = 16wd + 8 + 4hi + {2,3}
        const u32 x = hi ? A : C;             // value the other half needs
        const u32 y = hi ? B : D;
        const u32 sx = __shfl_xor(x, 32);     // hi0: other A ; hi1: other C
        const u32 sy = __shfl_xor(y, 32);
        union { u32 u[4]; f16x8 v; } fr;
        fr.u[0] = hi ? sx : A;                // k j=0,1
        fr.u[1] = hi ? sy : B;                // k j=2,3
        fr.u[2] = hi ? C : sx;                // k j=4,5
        fr.u[3] = hi ? D : sy;                // k j=6,7
        pA[sk * 2 + wd] = fr.v;
      }
    }

    // O += P V : 4 kv windows x 2 d-blocks
#pragma unroll
    for (int win = 0; win < 4; win++) {
      f16x8 vf0 = *reinterpret_cast<const f16x8*>(
          &Vb[l31 * 64 + (((win * 2 + hi) ^ fsw) << 3)]);
      f16x8 vf1 = *reinterpret_cast<const f16x8*>(
          &Vb[(32 + l31) * 64 + (((win * 2 + hi) ^ fsw) << 3)]);
      O0 = __builtin_amdgcn_mfma_f32_32x32x16_f16(pA[win], vf0, O0, 0, 0, 0);
      O1 = __builtin_amdgcn_mfma_f32_32x32x16_f16(pA[win], vf1, O1, 0, 0, 0);
    }
    cur ^= 1;
  }

  // epilogue: finish row sums (one xor-32), normalize, store
  lsum += __shfl_xor(lsum, 32);
  const int b = bh >> 4, h = bh & 15;
#pragma unroll
  for (int g = 0; g < 4; g++) {
#pragma unroll
    for (int rr = 0; rr < 4; rr++) {
      const int r = g * 4 + rr;
      const int qrow = rr + 8 * g + 4 * hi;
      const float inv = 1.f / __shfl(lsum, qrow, 64);
      const int n = q0 + 32 * w + qrow;
      u16* dst = AO + ((size_t)(b * SEQ + n)) * EMB + h * HD;
      dst[l31]      = f2h(O0[r] * inv);
      dst[32 + l31] = f2h(O1[r] * inv);
    }
  }
}

extern "C" void kernel_launch(void* const* d_in, const int* in_sizes, int n_in,
                              void* d_out, int out_size, void* d_ws, size_t ws_size,
                              hipStream_t stream) {
  (void)in_sizes; (void)n_in; (void)out_size; (void)ws_size;
  const float* x     = (const float*)d_in[0];
  const float* Wqkv  = (const float*)d_in[1];
  const float* bqkv  = (const float*)d_in[2];
  const float* Wproj = (const float*)d_in[3];
  const float* bproj = (const float*)d_in[4];
  float* out = (float*)d_out;

  const size_t NE = (size_t)BATCH * SEQ * EMB;       // 4,194,304
  u16* q    = (u16*)d_ws;
  u16* k    = q + NE;
  u16* vt   = k + NE;                                // [B,H,D,N]
  u16* aoxh = vt + NE;                               // ao aliases Xh
  u16* Wt   = aoxh + NE;
  u16* Wpt  = Wt + (size_t)NQKV * EMB;

  cvt_x<<<NE / 2048, 256, 0, stream>>>(x, aoxh);
  dim3 gw1(NQKV / 64, EMB / 64);
  cvt_wt<<<gw1, 256, 0, stream>>>(Wqkv, Wt, EMB, NQKV);
  dim3 gw2(EMB / 64, EMB / 64);
  cvt_wt<<<gw2, 256, 0, stream>>>(Wproj, Wpt, EMB, EMB);

  dim3 gq(NQKV / 128, (BATCH * SEQ) / 128);          // 24 x 32
  k_qkv<<<gq, 256, 0, stream>>>(aoxh, Wt, bqkv, q, k, vt);

  dim3 ga(SEQ / 64, BATCH * NH);                     // 32 x 32 = 1024 blocks
  k_attn<<<ga, 128, 0, stream>>>(q, k, vt, aoxh);

  dim3 gp(EMB / 128, (BATCH * SEQ) / 128);           // 8 x 32
  k_proj<<<gp, 256, 0, stream>>>(aoxh, Wpt, bproj, out);
}